// Round 1
// baseline (567.910 us; speedup 1.0000x reference)
//
#include <hip/hip_runtime.h>
#include <hip/hip_bf16.h>

// Problem constants
#define NROWS 131072
#define DDIM  64
#define KCODE 512

// Output layout (flat f32 concat, in reference return order)
#define QUANT_OFF 1LL
#define PERP_OFF  8388609LL
#define ENC_OFF   8388610LL
#define EMB_OFF   75497474LL
#define CS_OFF    75530242LL
#define EMAW_OFF  75530754LL

// Workspace layout (floats)
#define WS_COUNTS 0
#define WS_DW     512
#define WS_SSE    33280
#define WS_WNORM  33792
#define WS_ZERO_FLOATS 33281   // counts + dw + sse

// ---------------------------------------------------------------------------
// Kernel 1: per-code squared norms
__global__ void wnorm_kernel(const float* __restrict__ W, float* __restrict__ wnorm) {
    int k = blockIdx.x * blockDim.x + threadIdx.x;
    if (k < KCODE) {
        const float4* wr = reinterpret_cast<const float4*>(&W[(size_t)k * DDIM]);
        float s = 0.f;
#pragma unroll
        for (int i = 0; i < DDIM / 4; ++i) {
            float4 v = wr[i];
            s += v.x * v.x + v.y * v.y + v.z * v.z + v.w * v.w;
        }
        wnorm[k] = s;
    }
}

// ---------------------------------------------------------------------------
// Kernel 2: main — distances + argmin + quantized_st + sse + counts/dw/one-hot
// Block: 64 rows x 512 codes (4 chunks of 128). 128 threads, 8x8 per thread.
__global__ __launch_bounds__(128) void vq_main_kernel(
    const float* __restrict__ X, const float* __restrict__ W,
    const float* __restrict__ wnorm,
    float* __restrict__ counts, float* __restrict__ dwg, float* __restrict__ sse_g,
    float* __restrict__ outq, float* __restrict__ enc) {

    __shared__ float xT[64][68];    // [d][row], stride 68 -> 16B aligned, low conflicts
    __shared__ float wT[64][132];   // [d][code-in-chunk]
    __shared__ int   rowIdx[64];

    const int tid  = threadIdx.x;
    const int row0 = blockIdx.x * 64;
    const int rg = tid >> 4;        // 0..7  (row group: 8 rows each)
    const int cg = tid & 15;        // 0..15 (code group: 8 codes each)
    const int rg8 = rg * 8, cg8 = cg * 8;

    // stage X tile transposed
    for (int u = tid; u < 64 * 16; u += 128) {
        int r = u >> 4, d4 = (u & 15) << 2;
        float4 v = *reinterpret_cast<const float4*>(&X[(size_t)(row0 + r) * DDIM + d4]);
        xT[d4 + 0][r] = v.x; xT[d4 + 1][r] = v.y;
        xT[d4 + 2][r] = v.z; xT[d4 + 3][r] = v.w;
    }

    float bestV[8]; int bestI[8];
#pragma unroll
    for (int i = 0; i < 8; ++i) { bestV[i] = 3.4e38f; bestI[i] = 0; }

    for (int ch = 0; ch < 4; ++ch) {
        const int kbase = ch << 7;
        __syncthreads();   // covers xT staging (ch=0) and wT reuse (ch>0)
        for (int u = tid; u < 128 * 16; u += 128) {
            int c = u >> 4, d4 = (u & 15) << 2;
            float4 v = *reinterpret_cast<const float4*>(&W[(size_t)(kbase + c) * DDIM + d4]);
            wT[d4 + 0][c] = v.x; wT[d4 + 1][c] = v.y;
            wT[d4 + 2][c] = v.z; wT[d4 + 3][c] = v.w;
        }
        __syncthreads();

        float acc[8][8];
#pragma unroll
        for (int i = 0; i < 8; ++i)
#pragma unroll
            for (int j = 0; j < 8; ++j) acc[i][j] = 0.f;

#pragma unroll 8
        for (int d = 0; d < 64; ++d) {
            float4 xa = *reinterpret_cast<const float4*>(&xT[d][rg8]);
            float4 xb = *reinterpret_cast<const float4*>(&xT[d][rg8 + 4]);
            float4 wa = *reinterpret_cast<const float4*>(&wT[d][cg8]);
            float4 wb = *reinterpret_cast<const float4*>(&wT[d][cg8 + 4]);
            float xv[8] = {xa.x, xa.y, xa.z, xa.w, xb.x, xb.y, xb.z, xb.w};
            float wv[8] = {wa.x, wa.y, wa.z, wa.w, wb.x, wb.y, wb.z, wb.w};
#pragma unroll
            for (int i = 0; i < 8; ++i)
#pragma unroll
                for (int j = 0; j < 8; ++j)
                    acc[i][j] += xv[i] * wv[j];
        }

        // fold chunk scores into running argmin (ascending j preserves
        // first-min tie semantics within a thread)
        float4 wna = *reinterpret_cast<const float4*>(&wnorm[kbase + cg8]);
        float4 wnb = *reinterpret_cast<const float4*>(&wnorm[kbase + cg8 + 4]);
        float wn[8] = {wna.x, wna.y, wna.z, wna.w, wnb.x, wnb.y, wnb.z, wnb.w};
#pragma unroll
        for (int i = 0; i < 8; ++i)
#pragma unroll
            for (int j = 0; j < 8; ++j) {
                float s = wn[j] - 2.0f * acc[i][j];
                int ci = kbase + cg8 + j;
                if (s < bestV[i]) { bestV[i] = s; bestI[i] = ci; }
            }
    }

    // cross-lane argmin over the 16 code-groups (lanes sharing rg)
#pragma unroll
    for (int m = 8; m >= 1; m >>= 1) {
#pragma unroll
        for (int i = 0; i < 8; ++i) {
            float ov = __shfl_xor(bestV[i], m);
            int   oi = __shfl_xor(bestI[i], m);
            if (ov < bestV[i] || (ov == bestV[i] && oi < bestI[i])) {
                bestV[i] = ov; bestI[i] = oi;
            }
        }
    }
    if (cg == 0) {
#pragma unroll
        for (int i = 0; i < 8; ++i) rowIdx[rg8 + i] = bestI[i];
    }
    __syncthreads();

    // epilogue: quantized_st, sse, dw scatter, counts, one-hot
    float ssel = 0.f;
    for (int u = tid; u < 64 * 16; u += 128) {
        int r = u >> 4, d4 = (u & 15) << 2;
        int idx = rowIdx[r];
        float4 wv = *reinterpret_cast<const float4*>(&W[(size_t)idx * DDIM + d4]);
        float4 xv = *reinterpret_cast<const float4*>(&X[(size_t)(row0 + r) * DDIM + d4]);
        float dx = wv.x - xv.x, dy = wv.y - xv.y, dz = wv.z - xv.z, dw4 = wv.w - xv.w;
        ssel += dx * dx + dy * dy + dz * dz + dw4 * dw4;
        size_t ob = (size_t)(row0 + r) * DDIM + d4;
        // replicate reference: q_st = x + (q - x)
        outq[ob + 0] = xv.x + dx;
        outq[ob + 1] = xv.y + dy;
        outq[ob + 2] = xv.z + dz;
        outq[ob + 3] = xv.w + dw4;
        size_t db = (size_t)idx * DDIM + d4;
        atomicAdd(&dwg[db + 0], xv.x);
        atomicAdd(&dwg[db + 1], xv.y);
        atomicAdd(&dwg[db + 2], xv.z);
        atomicAdd(&dwg[db + 3], xv.w);
    }
#pragma unroll
    for (int m = 32; m >= 1; m >>= 1) ssel += __shfl_xor(ssel, m);
    if ((tid & 63) == 0) atomicAdd(sse_g, ssel);

    if (tid < 64) {
        int idx = rowIdx[tid];
        atomicAdd(&counts[idx], 1.0f);
        enc[(size_t)(row0 + tid) * KCODE + idx] = 1.0f;
    }
}

// ---------------------------------------------------------------------------
// Kernel 3: finalize — cluster-size norm, new_ema_w, new_embedding,
// perplexity, loss
__global__ __launch_bounds__(512) void finalize_kernel(
    const float* __restrict__ ema_w, const float* __restrict__ ema_cs,
    const float* __restrict__ counts, const float* __restrict__ dwg,
    const float* __restrict__ sse_g, float* __restrict__ out) {

    __shared__ float red[512];
    __shared__ float cs_sh[512];
    int t = threadIdx.x;

    float cnt = counts[t];
    float raw = ema_cs[t] * 0.99f + 0.01f * cnt;
    red[t] = raw;
    __syncthreads();
    for (int s = 256; s > 0; s >>= 1) {
        if (t < s) red[t] += red[t + s];
        __syncthreads();
    }
    float n = red[0];
    __syncthreads();

    float ncs = (raw + 1e-5f) / (n + (float)KCODE * 1e-5f) * n;
    out[CS_OFF + t] = ncs;
    cs_sh[t] = ncs;

    float avg = cnt / (float)NROWS;
    red[t] = avg * logf(avg + 1e-10f);
    __syncthreads();
    for (int s = 256; s > 0; s >>= 1) {
        if (t < s) red[t] += red[t + s];
        __syncthreads();
    }
    if (t == 0) {
        out[PERP_OFF] = expf(-red[0]);
        out[0] = 0.25f * sse_g[0] / ((float)NROWS * (float)DDIM);
    }
    __syncthreads();

    for (int i = t; i < KCODE * DDIM; i += 512) {
        float ne = ema_w[i] * 0.99f + 0.01f * dwg[i];
        out[EMAW_OFF + i] = ne;
        out[EMB_OFF + i] = ne / cs_sh[i >> 6];
    }
}

// ---------------------------------------------------------------------------
extern "C" void kernel_launch(void* const* d_in, const int* in_sizes, int n_in,
                              void* d_out, int out_size, void* d_ws, size_t ws_size,
                              hipStream_t stream) {
    const float* X      = (const float*)d_in[0];
    const float* W      = (const float*)d_in[1];
    const float* ema_w  = (const float*)d_in[2];
    const float* ema_cs = (const float*)d_in[3];
    float* out = (float*)d_out;
    float* ws  = (float*)d_ws;

    float* counts = ws + WS_COUNTS;
    float* dwg    = ws + WS_DW;
    float* sse    = ws + WS_SSE;
    float* wnorm  = ws + WS_WNORM;

    // zero accumulators (counts + dw + sse)
    hipMemsetAsync(d_ws, 0, (size_t)WS_ZERO_FLOATS * sizeof(float), stream);
    // zero the dense one-hot encodings region (268 MB)
    hipMemsetAsync(out + ENC_OFF, 0, (size_t)NROWS * KCODE * sizeof(float), stream);

    wnorm_kernel<<<1, 512, 0, stream>>>(W, wnorm);
    vq_main_kernel<<<NROWS / 64, 128, 0, stream>>>(X, W, wnorm, counts, dwg, sse,
                                                   out + QUANT_OFF, out + ENC_OFF);
    finalize_kernel<<<1, 512, 0, stream>>>(ema_w, ema_cs, counts, dwg, sse, out);
}

// Round 2
// 541.365 us; speedup vs baseline: 1.0490x; 1.0490x over previous
//
#include <hip/hip_runtime.h>

// Problem constants
#define NROWS 131072
#define DDIM  64
#define KCODE 512

// Output layout (flat f32 concat, reference return order)
#define QUANT_OFF 1LL
#define PERP_OFF  8388609LL
#define ENC_OFF   8388610LL
#define EMB_OFF   75497474LL
#define CS_OFF    75530242LL
#define EMAW_OFF  75530754LL

// Workspace layout (float offsets)
#define WS_COUNTS 0         // 512 f
#define WS_NEGWN  512       // 512 f  (-0.5*||w||^2)
#define WS_SSE    1024      // 1 f
#define WS_OFF    1040      // 512 int
#define WS_POS    1552      // 512 int
#define WS_IDX    2064      // 131072 int
#define WS_BUCKET 133136    // 131072 int
#define WS_DW     264208    // 32768 f
#define WS_WHI    296976    // 32768 ushort (16384 f slots)
#define WS_WMID   313360
#define WS_WLO    329744
// total 346128 floats = 1.39 MB

using short8 = __attribute__((ext_vector_type(8))) short;
using f32x4  = __attribute__((ext_vector_type(4))) float;

#define MFMA(a, b, c) __builtin_amdgcn_mfma_f32_16x16x32_bf16((a), (b), (c), 0, 0, 0)

__device__ inline unsigned short bf16_rne(float x) {
    unsigned u = __float_as_uint(x);
    unsigned r = u + 0x7FFFu + ((u >> 16) & 1u);
    return (unsigned short)(r >> 16);
}
__device__ inline float bf16_to_f(unsigned short h) {
    return __uint_as_float((unsigned)h << 16);
}
// split x = hi + mid + lo (each bf16), residual <= 2^-27 |x|
__device__ inline void split3(const float* v, short8& h8, short8& m8, short8& l8) {
#pragma unroll
    for (int j = 0; j < 8; ++j) {
        float x = v[j];
        unsigned short h = bf16_rne(x);
        float m_ = x - bf16_to_f(h);
        unsigned short m = bf16_rne(m_);
        float l_ = m_ - bf16_to_f(m);
        unsigned short l = bf16_rne(l_);
        h8[j] = (short)h; m8[j] = (short)m; l8[j] = (short)l;
    }
}

// ---------------------------------------------------------------------------
// negwn[k] = -0.5 * ||W_k||^2
__global__ void wnorm_kernel(const float* __restrict__ W, float* __restrict__ negwn) {
    int k = threadIdx.x;
    const float4* wr = reinterpret_cast<const float4*>(&W[(size_t)k * DDIM]);
    float s = 0.f;
#pragma unroll
    for (int i = 0; i < DDIM / 4; ++i) {
        float4 v = wr[i];
        s += v.x * v.x + v.y * v.y + v.z * v.z + v.w * v.w;
    }
    negwn[k] = -0.5f * s;
}

// Pre-split W into bf16 hi/mid/lo, packed in exact MFMA B-fragment lane order:
// chunk c (16 codes), lane l: code = c*16 + (l&15), k = kh*32 + (l>>4)*8 + j.
// Element index: (c*64 + l)*16 + kh*8 + j   -> lane-contiguous 32B, coalesced.
__global__ void wprep_kernel(const float* __restrict__ W, ushort* __restrict__ whi,
                             ushort* __restrict__ wmid, ushort* __restrict__ wlo) {
    int t = blockIdx.x * 256 + threadIdx.x;  // 0..2047
    int lane = t & 63;
    int code = (t >> 6) * 16 + (lane & 15);
    int kbase = (lane >> 4) * 8;
    int obase = t * 16;
#pragma unroll
    for (int kh = 0; kh < 2; ++kh) {
        float xbuf[8];
#pragma unroll
        for (int j = 0; j < 8; ++j) xbuf[j] = W[code * 64 + kh * 32 + kbase + j];
        short8 h8, m8, l8;
        split3(xbuf, h8, m8, l8);
#pragma unroll
        for (int j = 0; j < 8; ++j) {
            whi[obase + kh * 8 + j]  = (ushort)h8[j];
            wmid[obase + kh * 8 + j] = (ushort)m8[j];
            wlo[obase + kh * 8 + j]  = (ushort)l8[j];
        }
    }
}

// ---------------------------------------------------------------------------
// Main: 256 threads = 4 waves; wave owns 32 rows (two 16x16 A-tiles).
// Loops 32 chunks of 16 codes; 24 MFMA/chunk; running argmax of dot - ||w||^2/2.
__global__ __launch_bounds__(256) void vq_main_kernel(
    const float* __restrict__ X, const ushort* __restrict__ WHI,
    const ushort* __restrict__ WMID, const ushort* __restrict__ WLO,
    const float* __restrict__ negwn, const float* __restrict__ W,
    float* __restrict__ counts, float* __restrict__ sse_g,
    int* __restrict__ idx_out, float* __restrict__ outq, float* __restrict__ enc) {

    __shared__ int rowIdx[128];
    const int tid = threadIdx.x;
    const int wave = tid >> 6, lane = tid & 63;
    const int col = lane & 15, kg = lane >> 4;
    const int row0 = blockIdx.x * 128;
    const int rowbase = row0 + wave * 32;

    // Load + 3-way split the two X tiles (A-frag layout: row=lane&15, k=(lane>>4)*8+j)
    short8 xh[2][2], xm[2][2], xl[2][2];
#pragma unroll
    for (int t = 0; t < 2; ++t) {
        int row = rowbase + t * 16 + col;
#pragma unroll
        for (int kh = 0; kh < 2; ++kh) {
            const float4* p = reinterpret_cast<const float4*>(&X[row * 64 + kh * 32 + kg * 8]);
            float4 a = p[0], b = p[1];
            float xbuf[8] = {a.x, a.y, a.z, a.w, b.x, b.y, b.z, b.w};
            split3(xbuf, xh[t][kh], xm[t][kh], xl[t][kh]);
        }
    }

    float bestV[2][4]; int bestC[2][4];
#pragma unroll
    for (int t = 0; t < 2; ++t)
#pragma unroll
        for (int i = 0; i < 4; ++i) { bestV[t][i] = -3.4e38f; bestC[t][i] = 0; }

    for (int c = 0; c < 32; ++c) {
        const short8* ph = reinterpret_cast<const short8*>(&WHI[(c * 64 + lane) * 16]);
        const short8* pm = reinterpret_cast<const short8*>(&WMID[(c * 64 + lane) * 16]);
        const short8* pl = reinterpret_cast<const short8*>(&WLO[(c * 64 + lane) * 16]);
        short8 wh0 = ph[0], wh1 = ph[1];
        short8 wm0 = pm[0], wm1 = pm[1];
        short8 wl0 = pl[0], wl1 = pl[1];
        float wn = negwn[c * 16 + col];
#pragma unroll
        for (int t = 0; t < 2; ++t) {
            f32x4 acc = {0.f, 0.f, 0.f, 0.f};
            // small terms first: x_h*w_l, x_l*w_h, x_m*w_m, x_h*w_m, x_m*w_h, x_h*w_h
            acc = MFMA(xh[t][0], wl0, acc); acc = MFMA(xh[t][1], wl1, acc);
            acc = MFMA(xl[t][0], wh0, acc); acc = MFMA(xl[t][1], wh1, acc);
            acc = MFMA(xm[t][0], wm0, acc); acc = MFMA(xm[t][1], wm1, acc);
            acc = MFMA(xh[t][0], wm0, acc); acc = MFMA(xh[t][1], wm1, acc);
            acc = MFMA(xm[t][0], wh0, acc); acc = MFMA(xm[t][1], wh1, acc);
            acc = MFMA(xh[t][0], wh0, acc); acc = MFMA(xh[t][1], wh1, acc);
#pragma unroll
            for (int i = 0; i < 4; ++i) {
                float r = acc[i] + wn;   // = dot - ||w||^2/2 ; argmax r == argmin dist
                if (r > bestV[t][i]) { bestV[t][i] = r; bestC[t][i] = c; }
            }
        }
    }

    // cross-lane argmax over the 16 cols; ties -> lower code index
#pragma unroll
    for (int t = 0; t < 2; ++t)
#pragma unroll
        for (int i = 0; i < 4; ++i) {
            float v = bestV[t][i];
            int ix = bestC[t][i] * 16 + col;
#pragma unroll
            for (int m = 1; m <= 8; m <<= 1) {
                float ov = __shfl_xor(v, m);
                int   oi = __shfl_xor(ix, m);
                if (ov > v || (ov == v && oi < ix)) { v = ov; ix = oi; }
            }
            if (col == 0) rowIdx[wave * 32 + t * 16 + kg * 4 + i] = ix;
        }
    __syncthreads();

    // epilogue: quantized_st, sse, idx/counts/one-hot
    float ssel = 0.f;
    for (int u = tid; u < 128 * 16; u += 256) {
        int r = u >> 4, d4 = (u & 15) << 2;
        int ix = rowIdx[r];
        float4 wv = *reinterpret_cast<const float4*>(&W[ix * 64 + d4]);
        float4 xv = *reinterpret_cast<const float4*>(&X[(size_t)(row0 + r) * 64 + d4]);
        float dx = wv.x - xv.x, dy = wv.y - xv.y, dz = wv.z - xv.z, dw4 = wv.w - xv.w;
        ssel += dx * dx + dy * dy + dz * dz + dw4 * dw4;
        size_t ob = (size_t)(row0 + r) * 64 + d4;
        outq[ob + 0] = xv.x + dx;
        outq[ob + 1] = xv.y + dy;
        outq[ob + 2] = xv.z + dz;
        outq[ob + 3] = xv.w + dw4;
    }
#pragma unroll
    for (int m = 32; m >= 1; m >>= 1) ssel += __shfl_xor(ssel, m);
    if (lane == 0) atomicAdd(sse_g, ssel);

    if (tid < 128) {
        int ix = rowIdx[tid];
        idx_out[row0 + tid] = ix;
        atomicAdd(&counts[ix], 1.0f);
        enc[(size_t)(row0 + tid) * KCODE + ix] = 1.0f;
    }
}

// ---------------------------------------------------------------------------
// exclusive prefix of counts -> off, pos
__global__ void prefix_kernel(const float* __restrict__ counts,
                              int* __restrict__ off, int* __restrict__ pos) {
    __shared__ int tmp[512];
    int t = threadIdx.x;
    int c = (int)counts[t];
    tmp[t] = c;
    __syncthreads();
    int val = c;
    for (int s = 1; s < 512; s <<= 1) {
        int add = (t >= s) ? tmp[t - s] : 0;
        __syncthreads();
        val += add; tmp[t] = val;
        __syncthreads();
    }
    int excl = val - c;
    off[t] = excl; pos[t] = excl;
}

__global__ void scatter_kernel(const int* __restrict__ idx, int* __restrict__ pos,
                               int* __restrict__ bucket) {
    int i = blockIdx.x * 256 + threadIdx.x;
    int k = idx[i];
    int p = atomicAdd(&pos[k], 1);
    bucket[p] = i;
}

// per-code gather-sum: dw[k][d] = sum of X rows assigned to k (no atomics)
__global__ __launch_bounds__(256) void dwsum_kernel(
    const float* __restrict__ X, const int* __restrict__ off,
    const int* __restrict__ bucket, float* __restrict__ dw) {
    __shared__ float red[4][64];
    int k = blockIdx.x;
    int d = threadIdx.x & 63, g = threadIdx.x >> 6;
    int c0 = off[k];
    int c1 = (k == KCODE - 1) ? NROWS : off[k + 1];
    float a0 = 0.f, a1 = 0.f;
    int r = c0 + g;
    while (r + 4 < c1) {
        a0 += X[(size_t)bucket[r] * 64 + d];
        a1 += X[(size_t)bucket[r + 4] * 64 + d];
        r += 8;
    }
    if (r < c1) a0 += X[(size_t)bucket[r] * 64 + d];
    red[g][d] = a0 + a1;
    __syncthreads();
    if (g == 0)
        dw[k * 64 + d] = red[0][d] + red[1][d] + red[2][d] + red[3][d];
}

// ---------------------------------------------------------------------------
__global__ __launch_bounds__(512) void finalize_kernel(
    const float* __restrict__ ema_w, const float* __restrict__ ema_cs,
    const float* __restrict__ counts, const float* __restrict__ dw,
    const float* __restrict__ sse_g, float* __restrict__ out) {

    __shared__ float red[512];
    __shared__ float cs_sh[512];
    int t = threadIdx.x;

    float cnt = counts[t];
    float raw = ema_cs[t] * 0.99f + 0.01f * cnt;
    red[t] = raw;
    __syncthreads();
    for (int s = 256; s > 0; s >>= 1) {
        if (t < s) red[t] += red[t + s];
        __syncthreads();
    }
    float n = red[0];
    __syncthreads();

    float ncs = (raw + 1e-5f) / (n + (float)KCODE * 1e-5f) * n;
    out[CS_OFF + t] = ncs;
    cs_sh[t] = ncs;

    float avg = cnt / (float)NROWS;
    red[t] = avg * logf(avg + 1e-10f);
    __syncthreads();
    for (int s = 256; s > 0; s >>= 1) {
        if (t < s) red[t] += red[t + s];
        __syncthreads();
    }
    if (t == 0) {
        out[PERP_OFF] = expf(-red[0]);
        out[0] = 0.25f * sse_g[0] / ((float)NROWS * (float)DDIM);
    }
    __syncthreads();

    for (int i = t; i < KCODE * DDIM; i += 512) {
        float ne = ema_w[i] * 0.99f + 0.01f * dw[i];
        out[EMAW_OFF + i] = ne;
        out[EMB_OFF + i] = ne / cs_sh[i >> 6];
    }
}

// ---------------------------------------------------------------------------
extern "C" void kernel_launch(void* const* d_in, const int* in_sizes, int n_in,
                              void* d_out, int out_size, void* d_ws, size_t ws_size,
                              hipStream_t stream) {
    const float* X      = (const float*)d_in[0];
    const float* W      = (const float*)d_in[1];
    const float* ema_w  = (const float*)d_in[2];
    const float* ema_cs = (const float*)d_in[3];
    float* out = (float*)d_out;
    float* ws  = (float*)d_ws;

    float*  counts = ws + WS_COUNTS;
    float*  negwn  = ws + WS_NEGWN;
    float*  sse    = ws + WS_SSE;
    int*    off    = (int*)(ws + WS_OFF);
    int*    pos    = (int*)(ws + WS_POS);
    int*    idx    = (int*)(ws + WS_IDX);
    int*    bucket = (int*)(ws + WS_BUCKET);
    float*  dw     = ws + WS_DW;
    ushort* whi    = (ushort*)(ws + WS_WHI);
    ushort* wmid   = (ushort*)(ws + WS_WMID);
    ushort* wlo    = (ushort*)(ws + WS_WLO);

    // zero counts + sse
    hipMemsetAsync(d_ws, 0, (size_t)(WS_OFF) * sizeof(float), stream);
    // zero the dense one-hot encodings region (268 MB)
    hipMemsetAsync(out + ENC_OFF, 0, (size_t)NROWS * KCODE * sizeof(float), stream);

    wnorm_kernel<<<1, 512, 0, stream>>>(W, negwn);
    wprep_kernel<<<8, 256, 0, stream>>>(W, whi, wmid, wlo);
    vq_main_kernel<<<NROWS / 128, 256, 0, stream>>>(X, whi, wmid, wlo, negwn, W,
                                                    counts, sse, idx,
                                                    out + QUANT_OFF, out + ENC_OFF);
    prefix_kernel<<<1, 512, 0, stream>>>(counts, off, pos);
    scatter_kernel<<<NROWS / 256, 256, 0, stream>>>(idx, pos, bucket);
    dwsum_kernel<<<KCODE, 256, 0, stream>>>(X, off, bucket, dw);
    finalize_kernel<<<1, 512, 0, stream>>>(ema_w, ema_cs, counts, dw, sse, out);
}

// Round 3
// 298.776 us; speedup vs baseline: 1.9008x; 1.8119x over previous
//
#include <hip/hip_runtime.h>

// Problem constants
#define NROWS 131072
#define DDIM  64
#define KCODE 512

// Output layout (flat f32 concat, reference return order)
#define QUANT_OFF 1LL
#define PERP_OFF  8388609LL
#define ENC_OFF   8388610LL
#define EMB_OFF   75497474LL
#define CS_OFF    75530242LL
#define EMAW_OFF  75530754LL

// Workspace layout (float offsets)
#define WS_COUNTS 0         // 512 f
#define WS_NEGWN  512       // 512 f  (-0.5*||w||^2)
#define WS_SSE    1024      // 16 f (1 used)
#define WS_DW     1040      // 32768 f
#define WS_ZERO_FLOATS 33808  // counts+negwn+sse+dw zeroed each launch
#define WS_OFF    33808     // 512 int
#define WS_POS    34320     // 512 int
#define WS_IDX    34832     // 131072 int
#define WS_BUCKET 165904    // 131072 int (packed k<<17 | row)
#define WS_WHI    296976    // 32768 ushort (16384 f slots)
#define WS_WMID   313360
#define WS_WLO    329744
// total ~346128 floats = 1.39 MB

using short8 = __attribute__((ext_vector_type(8))) short;
using f32x4  = __attribute__((ext_vector_type(4))) float;

#define MFMA(a, b, c) __builtin_amdgcn_mfma_f32_16x16x32_bf16((a), (b), (c), 0, 0, 0)

__device__ inline unsigned short bf16_rne(float x) {
    unsigned u = __float_as_uint(x);
    unsigned r = u + 0x7FFFu + ((u >> 16) & 1u);
    return (unsigned short)(r >> 16);
}
__device__ inline float bf16_to_f(unsigned short h) {
    return __uint_as_float((unsigned)h << 16);
}
// split x = hi + mid + lo (each bf16), residual <= 2^-27 |x|
__device__ inline void split3(const float* v, short8& h8, short8& m8, short8& l8) {
#pragma unroll
    for (int j = 0; j < 8; ++j) {
        float x = v[j];
        unsigned short h = bf16_rne(x);
        float m_ = x - bf16_to_f(h);
        unsigned short m = bf16_rne(m_);
        float l_ = m_ - bf16_to_f(m);
        unsigned short l = bf16_rne(l_);
        h8[j] = (short)h; m8[j] = (short)m; l8[j] = (short)l;
    }
}

// ---------------------------------------------------------------------------
// negwn[k] = -0.5 * ||W_k||^2
__global__ void wnorm_kernel(const float* __restrict__ W, float* __restrict__ negwn) {
    int k = threadIdx.x;
    const float4* wr = reinterpret_cast<const float4*>(&W[(size_t)k * DDIM]);
    float s = 0.f;
#pragma unroll
    for (int i = 0; i < DDIM / 4; ++i) {
        float4 v = wr[i];
        s += v.x * v.x + v.y * v.y + v.z * v.z + v.w * v.w;
    }
    negwn[k] = -0.5f * s;
}

// Pre-split W into bf16 hi/mid/lo, packed in exact MFMA B-fragment lane order:
// chunk c (16 codes), lane l: code = c*16 + (l&15), k = kh*32 + (l>>4)*8 + j.
// Element index: (c*64 + l)*16 + kh*8 + j   -> lane-contiguous 32B, coalesced.
__global__ void wprep_kernel(const float* __restrict__ W, ushort* __restrict__ whi,
                             ushort* __restrict__ wmid, ushort* __restrict__ wlo) {
    int t = blockIdx.x * 256 + threadIdx.x;  // 0..2047
    int lane = t & 63;
    int code = (t >> 6) * 16 + (lane & 15);
    int kbase = (lane >> 4) * 8;
    int obase = t * 16;
#pragma unroll
    for (int kh = 0; kh < 2; ++kh) {
        float xbuf[8];
#pragma unroll
        for (int j = 0; j < 8; ++j) xbuf[j] = W[code * 64 + kh * 32 + kbase + j];
        short8 h8, m8, l8;
        split3(xbuf, h8, m8, l8);
#pragma unroll
        for (int j = 0; j < 8; ++j) {
            whi[obase + kh * 8 + j]  = (ushort)h8[j];
            wmid[obase + kh * 8 + j] = (ushort)m8[j];
            wlo[obase + kh * 8 + j]  = (ushort)l8[j];
        }
    }
}

// ---------------------------------------------------------------------------
// Main: 256 threads = 4 waves; wave owns 32 rows (two 16x16 A-tiles).
// Loops 32 chunks of 16 codes; 24 MFMA/chunk; running argmax of dot - ||w||^2/2.
__global__ __launch_bounds__(256) void vq_main_kernel(
    const float* __restrict__ X, const ushort* __restrict__ WHI,
    const ushort* __restrict__ WMID, const ushort* __restrict__ WLO,
    const float* __restrict__ negwn, const float* __restrict__ W,
    float* __restrict__ counts, float* __restrict__ sse_g,
    int* __restrict__ idx_out, float* __restrict__ outq, float* __restrict__ enc) {

    __shared__ int rowIdx[128];
    const int tid = threadIdx.x;
    const int wave = tid >> 6, lane = tid & 63;
    const int col = lane & 15, kg = lane >> 4;
    const int row0 = blockIdx.x * 128;
    const int rowbase = row0 + wave * 32;

    // Load + 3-way split the two X tiles (A-frag layout: row=lane&15, k=(lane>>4)*8+j)
    short8 xh[2][2], xm[2][2], xl[2][2];
#pragma unroll
    for (int t = 0; t < 2; ++t) {
        int row = rowbase + t * 16 + col;
#pragma unroll
        for (int kh = 0; kh < 2; ++kh) {
            const float4* p = reinterpret_cast<const float4*>(&X[row * 64 + kh * 32 + kg * 8]);
            float4 a = p[0], b = p[1];
            float xbuf[8] = {a.x, a.y, a.z, a.w, b.x, b.y, b.z, b.w};
            split3(xbuf, xh[t][kh], xm[t][kh], xl[t][kh]);
        }
    }

    float bestV[2][4]; int bestC[2][4];
#pragma unroll
    for (int t = 0; t < 2; ++t)
#pragma unroll
        for (int i = 0; i < 4; ++i) { bestV[t][i] = -3.4e38f; bestC[t][i] = 0; }

    for (int c = 0; c < 32; ++c) {
        const short8* ph = reinterpret_cast<const short8*>(&WHI[(c * 64 + lane) * 16]);
        const short8* pm = reinterpret_cast<const short8*>(&WMID[(c * 64 + lane) * 16]);
        const short8* pl = reinterpret_cast<const short8*>(&WLO[(c * 64 + lane) * 16]);
        short8 wh0 = ph[0], wh1 = ph[1];
        short8 wm0 = pm[0], wm1 = pm[1];
        short8 wl0 = pl[0], wl1 = pl[1];
        float wn = negwn[c * 16 + col];
#pragma unroll
        for (int t = 0; t < 2; ++t) {
            f32x4 acc = {0.f, 0.f, 0.f, 0.f};
            // small terms first: x_h*w_l, x_l*w_h, x_m*w_m, x_h*w_m, x_m*w_h, x_h*w_h
            acc = MFMA(xh[t][0], wl0, acc); acc = MFMA(xh[t][1], wl1, acc);
            acc = MFMA(xl[t][0], wh0, acc); acc = MFMA(xl[t][1], wh1, acc);
            acc = MFMA(xm[t][0], wm0, acc); acc = MFMA(xm[t][1], wm1, acc);
            acc = MFMA(xh[t][0], wm0, acc); acc = MFMA(xh[t][1], wm1, acc);
            acc = MFMA(xm[t][0], wh0, acc); acc = MFMA(xm[t][1], wh1, acc);
            acc = MFMA(xh[t][0], wh0, acc); acc = MFMA(xh[t][1], wh1, acc);
#pragma unroll
            for (int i = 0; i < 4; ++i) {
                float r = acc[i] + wn;   // = dot - ||w||^2/2 ; argmax r == argmin dist
                if (r > bestV[t][i]) { bestV[t][i] = r; bestC[t][i] = c; }
            }
        }
    }

    // cross-lane argmax over the 16 cols; ties -> lower code index
#pragma unroll
    for (int t = 0; t < 2; ++t)
#pragma unroll
        for (int i = 0; i < 4; ++i) {
            float v = bestV[t][i];
            int ix = bestC[t][i] * 16 + col;
#pragma unroll
            for (int m = 1; m <= 8; m <<= 1) {
                float ov = __shfl_xor(v, m);
                int   oi = __shfl_xor(ix, m);
                if (ov > v || (ov == v && oi < ix)) { v = ov; ix = oi; }
            }
            if (col == 0) rowIdx[wave * 32 + t * 16 + kg * 4 + i] = ix;
        }
    __syncthreads();

    // epilogue: quantized_st, sse, idx/counts/one-hot
    float ssel = 0.f;
    for (int u = tid; u < 128 * 16; u += 256) {
        int r = u >> 4, d4 = (u & 15) << 2;
        int ix = rowIdx[r];
        float4 wv = *reinterpret_cast<const float4*>(&W[ix * 64 + d4]);
        float4 xv = *reinterpret_cast<const float4*>(&X[(size_t)(row0 + r) * 64 + d4]);
        float dx = wv.x - xv.x, dy = wv.y - xv.y, dz = wv.z - xv.z, dw4 = wv.w - xv.w;
        ssel += dx * dx + dy * dy + dz * dz + dw4 * dw4;
        size_t ob = (size_t)(row0 + r) * 64 + d4;
        outq[ob + 0] = xv.x + dx;
        outq[ob + 1] = xv.y + dy;
        outq[ob + 2] = xv.z + dz;
        outq[ob + 3] = xv.w + dw4;
    }
#pragma unroll
    for (int m = 32; m >= 1; m >>= 1) ssel += __shfl_xor(ssel, m);
    if (lane == 0) atomicAdd(sse_g, ssel);

    if (tid < 128) {
        int ix = rowIdx[tid];
        idx_out[row0 + tid] = ix;
        atomicAdd(&counts[ix], 1.0f);
        enc[(size_t)(row0 + tid) * KCODE + ix] = 1.0f;
    }
}

// ---------------------------------------------------------------------------
// exclusive prefix of counts -> off, pos
__global__ void prefix_kernel(const float* __restrict__ counts,
                              int* __restrict__ off, int* __restrict__ pos) {
    __shared__ int tmp[512];
    int t = threadIdx.x;
    int c = (int)counts[t];
    tmp[t] = c;
    __syncthreads();
    int val = c;
    for (int s = 1; s < 512; s <<= 1) {
        int add = (t >= s) ? tmp[t - s] : 0;
        __syncthreads();
        val += add; tmp[t] = val;
        __syncthreads();
    }
    int excl = val - c;
    off[t] = excl; pos[t] = excl;
}

// bucket[p] = (k << 17) | row   (k < 2^9, row < 2^17)
__global__ void scatter_kernel(const int* __restrict__ idx, int* __restrict__ pos,
                               int* __restrict__ bucket) {
    int i = blockIdx.x * 256 + threadIdx.x;
    int k = idx[i];
    int p = atomicAdd(&pos[k], 1);
    bucket[p] = (k << 17) | i;
}

// Segmented gather-sum over the sorted bucket: one wave per 16 entries,
// lane = dim, flush partial sum via atomicAdd on code-run boundaries.
__global__ __launch_bounds__(256) void dwsum_kernel(
    const float* __restrict__ X, const int* __restrict__ bucket,
    float* __restrict__ dw) {
    const int lane = threadIdx.x & 63;
    const int gwave = (blockIdx.x * 256 + threadIdx.x) >> 6;
    const int r0 = gwave * 16;
    int v = bucket[r0];
    int k = v >> 17, row = v & 0x1FFFF;
    float acc = 0.f;
#pragma unroll
    for (int i = 0; i < 16; ++i) {
        acc += X[(size_t)row * 64 + lane];
        if (i + 1 < 16) {
            int nv = bucket[r0 + i + 1];
            int nk = nv >> 17, nrow = nv & 0x1FFFF;
            if (nk != k) {                // wave-uniform branch
                atomicAdd(&dw[k * 64 + lane], acc);
                acc = 0.f; k = nk;
            }
            row = nrow;
        }
    }
    atomicAdd(&dw[k * 64 + lane], acc);
}

// ---------------------------------------------------------------------------
__global__ __launch_bounds__(512) void finalize_kernel(
    const float* __restrict__ ema_w, const float* __restrict__ ema_cs,
    const float* __restrict__ counts, const float* __restrict__ dw,
    const float* __restrict__ sse_g, float* __restrict__ out) {

    __shared__ float red[512];
    __shared__ float cs_sh[512];
    int t = threadIdx.x;

    float cnt = counts[t];
    float raw = ema_cs[t] * 0.99f + 0.01f * cnt;
    red[t] = raw;
    __syncthreads();
    for (int s = 256; s > 0; s >>= 1) {
        if (t < s) red[t] += red[t + s];
        __syncthreads();
    }
    float n = red[0];
    __syncthreads();

    float ncs = (raw + 1e-5f) / (n + (float)KCODE * 1e-5f) * n;
    out[CS_OFF + t] = ncs;
    cs_sh[t] = ncs;

    float avg = cnt / (float)NROWS;
    red[t] = avg * logf(avg + 1e-10f);
    __syncthreads();
    for (int s = 256; s > 0; s >>= 1) {
        if (t < s) red[t] += red[t + s];
        __syncthreads();
    }
    if (t == 0) {
        out[PERP_OFF] = expf(-red[0]);
        out[0] = 0.25f * sse_g[0] / ((float)NROWS * (float)DDIM);
    }
    __syncthreads();

    for (int i = t; i < KCODE * DDIM; i += 512) {
        float ne = ema_w[i] * 0.99f + 0.01f * dw[i];
        out[EMAW_OFF + i] = ne;
        out[EMB_OFF + i] = ne / cs_sh[i >> 6];
    }
}

// ---------------------------------------------------------------------------
extern "C" void kernel_launch(void* const* d_in, const int* in_sizes, int n_in,
                              void* d_out, int out_size, void* d_ws, size_t ws_size,
                              hipStream_t stream) {
    const float* X      = (const float*)d_in[0];
    const float* W      = (const float*)d_in[1];
    const float* ema_w  = (const float*)d_in[2];
    const float* ema_cs = (const float*)d_in[3];
    float* out = (float*)d_out;
    float* ws  = (float*)d_ws;

    float*  counts = ws + WS_COUNTS;
    float*  negwn  = ws + WS_NEGWN;
    float*  sse    = ws + WS_SSE;
    float*  dw     = ws + WS_DW;
    int*    off    = (int*)(ws + WS_OFF);
    int*    pos    = (int*)(ws + WS_POS);
    int*    idx    = (int*)(ws + WS_IDX);
    int*    bucket = (int*)(ws + WS_BUCKET);
    ushort* whi    = (ushort*)(ws + WS_WHI);
    ushort* wmid   = (ushort*)(ws + WS_WMID);
    ushort* wlo    = (ushort*)(ws + WS_WLO);

    // zero counts + negwn + sse + dw
    hipMemsetAsync(d_ws, 0, (size_t)WS_ZERO_FLOATS * sizeof(float), stream);
    // zero the dense one-hot encodings region (268 MB)
    hipMemsetAsync(out + ENC_OFF, 0, (size_t)NROWS * KCODE * sizeof(float), stream);

    wnorm_kernel<<<1, 512, 0, stream>>>(W, negwn);
    wprep_kernel<<<8, 256, 0, stream>>>(W, whi, wmid, wlo);
    vq_main_kernel<<<NROWS / 128, 256, 0, stream>>>(X, whi, wmid, wlo, negwn, W,
                                                    counts, sse, idx,
                                                    out + QUANT_OFF, out + ENC_OFF);
    prefix_kernel<<<1, 512, 0, stream>>>(counts, off, pos);
    scatter_kernel<<<NROWS / 256, 256, 0, stream>>>(idx, pos, bucket);
    dwsum_kernel<<<NROWS / 16 / 4, 256, 0, stream>>>(X, bucket, dw);
    finalize_kernel<<<1, 512, 0, stream>>>(ema_w, ema_cs, counts, dw, sse, out);
}

// Round 4
// 265.591 us; speedup vs baseline: 2.1383x; 1.1249x over previous
//
#include <hip/hip_runtime.h>

// Problem constants
#define NROWS 131072
#define DDIM  64
#define KCODE 512

// Output layout (flat f32 concat, reference return order)
#define QUANT_OFF 1LL
#define PERP_OFF  8388609LL
#define ENC_OFF   8388610LL
#define EMB_OFF   75497474LL
#define CS_OFF    75530242LL
#define EMAW_OFF  75530754LL

// Workspace layout (float offsets)
#define WS_COUNTS 0         // 512 f
#define WS_NEGWN  512       // 512 f  (-0.5*||w||^2)
#define WS_SSE    1024      // 16 f (1 used)
#define WS_DW     1040      // 32768 f
#define WS_ZERO_FLOATS 33808  // counts+negwn+sse+dw zeroed each launch
#define WS_OFF    33808     // 512 int
#define WS_POS    34320     // 512 int
#define WS_IDX    34832     // 131072 int
#define WS_BUCKET 165904    // 131072 int (packed k<<17 | row)
#define WS_WHI    296976    // 32768 ushort (16384 f slots)
#define WS_WMID   313360
#define WS_WLO    329744
// total ~346128 floats = 1.39 MB

using short8 = __attribute__((ext_vector_type(8))) short;
using f32x4  = __attribute__((ext_vector_type(4))) float;

#define MFMA(a, b, c) __builtin_amdgcn_mfma_f32_16x16x32_bf16((a), (b), (c), 0, 0, 0)

__device__ inline unsigned short bf16_rne(float x) {
    unsigned u = __float_as_uint(x);
    unsigned r = u + 0x7FFFu + ((u >> 16) & 1u);
    return (unsigned short)(r >> 16);
}
__device__ inline float bf16_to_f(unsigned short h) {
    return __uint_as_float((unsigned)h << 16);
}
// split x = hi + mid + lo (each bf16), residual <= 2^-27 |x|
__device__ inline void split3(const float* v, short8& h8, short8& m8, short8& l8) {
#pragma unroll
    for (int j = 0; j < 8; ++j) {
        float x = v[j];
        unsigned short h = bf16_rne(x);
        float m_ = x - bf16_to_f(h);
        unsigned short m = bf16_rne(m_);
        float l_ = m_ - bf16_to_f(m);
        unsigned short l = bf16_rne(l_);
        h8[j] = (short)h; m8[j] = (short)m; l8[j] = (short)l;
    }
}

// ---------------------------------------------------------------------------
// negwn[k] = -0.5 * ||W_k||^2
__global__ void wnorm_kernel(const float* __restrict__ W, float* __restrict__ negwn) {
    int k = threadIdx.x;
    const float4* wr = reinterpret_cast<const float4*>(&W[(size_t)k * DDIM]);
    float s = 0.f;
#pragma unroll
    for (int i = 0; i < DDIM / 4; ++i) {
        float4 v = wr[i];
        s += v.x * v.x + v.y * v.y + v.z * v.z + v.w * v.w;
    }
    negwn[k] = -0.5f * s;
}

// Pre-split W into bf16 hi/mid/lo, packed in exact MFMA B-fragment lane order:
// chunk c (16 codes), lane l: code = c*16 + (l&15), k = kh*32 + (l>>4)*8 + j.
// Element index: (c*64 + l)*16 + kh*8 + j   -> lane-contiguous 32B, coalesced.
__global__ void wprep_kernel(const float* __restrict__ W, ushort* __restrict__ whi,
                             ushort* __restrict__ wmid, ushort* __restrict__ wlo) {
    int t = blockIdx.x * 256 + threadIdx.x;  // 0..2047
    int lane = t & 63;
    int code = (t >> 6) * 16 + (lane & 15);
    int kbase = (lane >> 4) * 8;
    int obase = t * 16;
#pragma unroll
    for (int kh = 0; kh < 2; ++kh) {
        float xbuf[8];
#pragma unroll
        for (int j = 0; j < 8; ++j) xbuf[j] = W[code * 64 + kh * 32 + kbase + j];
        short8 h8, m8, l8;
        split3(xbuf, h8, m8, l8);
#pragma unroll
        for (int j = 0; j < 8; ++j) {
            whi[obase + kh * 8 + j]  = (ushort)h8[j];
            wmid[obase + kh * 8 + j] = (ushort)m8[j];
            wlo[obase + kh * 8 + j]  = (ushort)l8[j];
        }
    }
}

// ---------------------------------------------------------------------------
// Main: 256 threads = 4 waves; wave owns 32 rows (two 16x16 A-tiles).
// Loops 32 chunks of 16 codes; 24 MFMA/chunk; running argmax of dot - ||w||^2/2.
// Epilogue ALSO streams the full dense one-hot rows (no separate memset).
__global__ __launch_bounds__(256) void vq_main_kernel(
    const float* __restrict__ X, const ushort* __restrict__ WHI,
    const ushort* __restrict__ WMID, const ushort* __restrict__ WLO,
    const float* __restrict__ negwn, const float* __restrict__ W,
    float* __restrict__ counts, float* __restrict__ sse_g,
    int* __restrict__ idx_out, float* __restrict__ outq, float* __restrict__ enc) {

    __shared__ int rowIdx[128];
    const int tid = threadIdx.x;
    const int wave = tid >> 6, lane = tid & 63;
    const int col = lane & 15, kg = lane >> 4;
    const int row0 = blockIdx.x * 128;
    const int rowbase = row0 + wave * 32;

    // Load + 3-way split the two X tiles (A-frag layout: row=lane&15, k=(lane>>4)*8+j)
    short8 xh[2][2], xm[2][2], xl[2][2];
#pragma unroll
    for (int t = 0; t < 2; ++t) {
        int row = rowbase + t * 16 + col;
#pragma unroll
        for (int kh = 0; kh < 2; ++kh) {
            const float4* p = reinterpret_cast<const float4*>(&X[row * 64 + kh * 32 + kg * 8]);
            float4 a = p[0], b = p[1];
            float xbuf[8] = {a.x, a.y, a.z, a.w, b.x, b.y, b.z, b.w};
            split3(xbuf, xh[t][kh], xm[t][kh], xl[t][kh]);
        }
    }

    float bestV[2][4]; int bestC[2][4];
#pragma unroll
    for (int t = 0; t < 2; ++t)
#pragma unroll
        for (int i = 0; i < 4; ++i) { bestV[t][i] = -3.4e38f; bestC[t][i] = 0; }

    for (int c = 0; c < 32; ++c) {
        const short8* ph = reinterpret_cast<const short8*>(&WHI[(c * 64 + lane) * 16]);
        const short8* pm = reinterpret_cast<const short8*>(&WMID[(c * 64 + lane) * 16]);
        const short8* pl = reinterpret_cast<const short8*>(&WLO[(c * 64 + lane) * 16]);
        short8 wh0 = ph[0], wh1 = ph[1];
        short8 wm0 = pm[0], wm1 = pm[1];
        short8 wl0 = pl[0], wl1 = pl[1];
        float wn = negwn[c * 16 + col];
#pragma unroll
        for (int t = 0; t < 2; ++t) {
            f32x4 acc = {0.f, 0.f, 0.f, 0.f};
            // small terms first: x_h*w_l, x_l*w_h, x_m*w_m, x_h*w_m, x_m*w_h, x_h*w_h
            acc = MFMA(xh[t][0], wl0, acc); acc = MFMA(xh[t][1], wl1, acc);
            acc = MFMA(xl[t][0], wh0, acc); acc = MFMA(xl[t][1], wh1, acc);
            acc = MFMA(xm[t][0], wm0, acc); acc = MFMA(xm[t][1], wm1, acc);
            acc = MFMA(xh[t][0], wm0, acc); acc = MFMA(xh[t][1], wm1, acc);
            acc = MFMA(xm[t][0], wh0, acc); acc = MFMA(xm[t][1], wh1, acc);
            acc = MFMA(xh[t][0], wh0, acc); acc = MFMA(xh[t][1], wh1, acc);
#pragma unroll
            for (int i = 0; i < 4; ++i) {
                float r = acc[i] + wn;   // = dot - ||w||^2/2 ; argmax r == argmin dist
                if (r > bestV[t][i]) { bestV[t][i] = r; bestC[t][i] = c; }
            }
        }
    }

    // cross-lane argmax over the 16 cols; ties -> lower code index
#pragma unroll
    for (int t = 0; t < 2; ++t)
#pragma unroll
        for (int i = 0; i < 4; ++i) {
            float v = bestV[t][i];
            int ix = bestC[t][i] * 16 + col;
#pragma unroll
            for (int m = 1; m <= 8; m <<= 1) {
                float ov = __shfl_xor(v, m);
                int   oi = __shfl_xor(ix, m);
                if (ov > v || (ov == v && oi < ix)) { v = ov; ix = oi; }
            }
            if (col == 0) rowIdx[wave * 32 + t * 16 + kg * 4 + i] = ix;
        }
    __syncthreads();

    // epilogue 1: quantized_st, sse
    float ssel = 0.f;
    for (int u = tid; u < 128 * 16; u += 256) {
        int r = u >> 4, d4 = (u & 15) << 2;
        int ix = rowIdx[r];
        float4 wv = *reinterpret_cast<const float4*>(&W[ix * 64 + d4]);
        float4 xv = *reinterpret_cast<const float4*>(&X[(size_t)(row0 + r) * 64 + d4]);
        float dx = wv.x - xv.x, dy = wv.y - xv.y, dz = wv.z - xv.z, dw4 = wv.w - xv.w;
        ssel += dx * dx + dy * dy + dz * dz + dw4 * dw4;
        size_t ob = (size_t)(row0 + r) * 64 + d4;
        outq[ob + 0] = xv.x + dx;
        outq[ob + 1] = xv.y + dy;
        outq[ob + 2] = xv.z + dz;
        outq[ob + 3] = xv.w + dw4;
    }
#pragma unroll
    for (int m = 32; m >= 1; m >>= 1) ssel += __shfl_xor(ssel, m);
    if (lane == 0) atomicAdd(sse_g, ssel);

    if (tid < 128) {
        int ix = rowIdx[tid];
        idx_out[row0 + tid] = ix;
        atomicAdd(&counts[ix], 1.0f);
    }

    // epilogue 2: stream the dense one-hot rows.
    // enc base is 8-mod-16 bytes -> float2 is the widest aligned store.
    // Iteration i: all 256 threads write row i (256 float2 = 2KB contiguous).
    const int t2 = tid * 2;
#pragma unroll 4
    for (int r = 0; r < 128; ++r) {
        int ix = rowIdx[r];
        float2 v;
        v.x = (ix == t2) ? 1.0f : 0.0f;
        v.y = (ix == t2 + 1) ? 1.0f : 0.0f;
        *reinterpret_cast<float2*>(&enc[((size_t)(row0 + r) << 9) + t2]) = v;
    }
}

// ---------------------------------------------------------------------------
// exclusive prefix of counts -> off, pos
__global__ void prefix_kernel(const float* __restrict__ counts,
                              int* __restrict__ off, int* __restrict__ pos) {
    __shared__ int tmp[512];
    int t = threadIdx.x;
    int c = (int)counts[t];
    tmp[t] = c;
    __syncthreads();
    int val = c;
    for (int s = 1; s < 512; s <<= 1) {
        int add = (t >= s) ? tmp[t - s] : 0;
        __syncthreads();
        val += add; tmp[t] = val;
        __syncthreads();
    }
    int excl = val - c;
    off[t] = excl; pos[t] = excl;
}

// bucket[p] = (k << 17) | row   (k < 2^9, row < 2^17)
__global__ void scatter_kernel(const int* __restrict__ idx, int* __restrict__ pos,
                               int* __restrict__ bucket) {
    int i = blockIdx.x * 256 + threadIdx.x;
    int k = idx[i];
    int p = atomicAdd(&pos[k], 1);
    bucket[p] = (k << 17) | i;
}

// Segmented gather-sum over the sorted bucket: one wave per 16 entries,
// lane = dim, flush partial sum via atomicAdd on code-run boundaries.
__global__ __launch_bounds__(256) void dwsum_kernel(
    const float* __restrict__ X, const int* __restrict__ bucket,
    float* __restrict__ dw) {
    const int lane = threadIdx.x & 63;
    const int gwave = (blockIdx.x * 256 + threadIdx.x) >> 6;
    const int r0 = gwave * 16;
    int v = bucket[r0];
    int k = v >> 17, row = v & 0x1FFFF;
    float acc = 0.f;
#pragma unroll
    for (int i = 0; i < 16; ++i) {
        acc += X[(size_t)row * 64 + lane];
        if (i + 1 < 16) {
            int nv = bucket[r0 + i + 1];
            int nk = nv >> 17, nrow = nv & 0x1FFFF;
            if (nk != k) {                // wave-uniform branch
                atomicAdd(&dw[k * 64 + lane], acc);
                acc = 0.f; k = nk;
            }
            row = nrow;
        }
    }
    atomicAdd(&dw[k * 64 + lane], acc);
}

// ---------------------------------------------------------------------------
__global__ __launch_bounds__(512) void finalize_kernel(
    const float* __restrict__ ema_w, const float* __restrict__ ema_cs,
    const float* __restrict__ counts, const float* __restrict__ dw,
    const float* __restrict__ sse_g, float* __restrict__ out) {

    __shared__ float red[512];
    __shared__ float cs_sh[512];
    int t = threadIdx.x;

    float cnt = counts[t];
    float raw = ema_cs[t] * 0.99f + 0.01f * cnt;
    red[t] = raw;
    __syncthreads();
    for (int s = 256; s > 0; s >>= 1) {
        if (t < s) red[t] += red[t + s];
        __syncthreads();
    }
    float n = red[0];
    __syncthreads();

    float ncs = (raw + 1e-5f) / (n + (float)KCODE * 1e-5f) * n;
    out[CS_OFF + t] = ncs;
    cs_sh[t] = ncs;

    float avg = cnt / (float)NROWS;
    red[t] = avg * logf(avg + 1e-10f);
    __syncthreads();
    for (int s = 256; s > 0; s >>= 1) {
        if (t < s) red[t] += red[t + s];
        __syncthreads();
    }
    if (t == 0) {
        out[PERP_OFF] = expf(-red[0]);
        out[0] = 0.25f * sse_g[0] / ((float)NROWS * (float)DDIM);
    }
    __syncthreads();

    for (int i = t; i < KCODE * DDIM; i += 512) {
        float ne = ema_w[i] * 0.99f + 0.01f * dw[i];
        out[EMAW_OFF + i] = ne;
        out[EMB_OFF + i] = ne / cs_sh[i >> 6];
    }
}

// ---------------------------------------------------------------------------
extern "C" void kernel_launch(void* const* d_in, const int* in_sizes, int n_in,
                              void* d_out, int out_size, void* d_ws, size_t ws_size,
                              hipStream_t stream) {
    const float* X      = (const float*)d_in[0];
    const float* W      = (const float*)d_in[1];
    const float* ema_w  = (const float*)d_in[2];
    const float* ema_cs = (const float*)d_in[3];
    float* out = (float*)d_out;
    float* ws  = (float*)d_ws;

    float*  counts = ws + WS_COUNTS;
    float*  negwn  = ws + WS_NEGWN;
    float*  sse    = ws + WS_SSE;
    float*  dw     = ws + WS_DW;
    int*    off    = (int*)(ws + WS_OFF);
    int*    pos    = (int*)(ws + WS_POS);
    int*    idx    = (int*)(ws + WS_IDX);
    int*    bucket = (int*)(ws + WS_BUCKET);
    ushort* whi    = (ushort*)(ws + WS_WHI);
    ushort* wmid   = (ushort*)(ws + WS_WMID);
    ushort* wlo    = (ushort*)(ws + WS_WLO);

    // zero counts + negwn + sse + dw (small; one-hot region now written fully
    // by vq_main's epilogue, no 268MB memset)
    hipMemsetAsync(d_ws, 0, (size_t)WS_ZERO_FLOATS * sizeof(float), stream);

    wnorm_kernel<<<1, 512, 0, stream>>>(W, negwn);
    wprep_kernel<<<8, 256, 0, stream>>>(W, whi, wmid, wlo);
    vq_main_kernel<<<NROWS / 128, 256, 0, stream>>>(X, whi, wmid, wlo, negwn, W,
                                                    counts, sse, idx,
                                                    out + QUANT_OFF, out + ENC_OFF);
    prefix_kernel<<<1, 512, 0, stream>>>(counts, off, pos);
    scatter_kernel<<<NROWS / 256, 256, 0, stream>>>(idx, pos, bucket);
    dwsum_kernel<<<NROWS / 16 / 4, 256, 0, stream>>>(X, bucket, dw);
    finalize_kernel<<<1, 512, 0, stream>>>(ema_w, ema_cs, counts, dw, sse, out);
}

// Round 6
// 250.012 us; speedup vs baseline: 2.2715x; 1.0623x over previous
//
#include <hip/hip_runtime.h>

// Problem constants
#define NROWS 131072
#define DDIM  64
#define KCODE 512

// Output layout (flat f32 concat, reference return order)
#define QUANT_OFF 1LL
#define PERP_OFF  8388609LL
#define ENC_OFF   8388610LL
#define EMB_OFF   75497474LL
#define CS_OFF    75530242LL
#define EMAW_OFF  75530754LL

// Workspace layout (float offsets)
#define WS_COUNTS 0         // 512 f
#define WS_NEGWN  512       // 512 f  (-0.5*||w||^2)
#define WS_SSE    1024      // 16 f (1 used)
#define WS_DW     1040      // 32768 f
#define WS_ZERO_FLOATS 33808  // counts+negwn+sse+dw zeroed each launch
#define WS_OFF    33808     // 512 int
#define WS_POS    34320     // 512 int
#define WS_IDX    34832     // 131072 int
#define WS_BUCKET 165904    // 131072 int (packed k<<17 | row)
#define WS_WHI    296976    // 32768 ushort (16384 f slots)
#define WS_WMID   313360
#define WS_WLO    329744
// total ~346128 floats = 1.39 MB

using short8 = __attribute__((ext_vector_type(8))) short;
using f32x4  = __attribute__((ext_vector_type(4))) float;
using f32x2  = __attribute__((ext_vector_type(2))) float;

#define MFMA(a, b, c) __builtin_amdgcn_mfma_f32_16x16x32_bf16((a), (b), (c), 0, 0, 0)

__device__ inline unsigned short bf16_rne(float x) {
    unsigned u = __float_as_uint(x);
    unsigned r = u + 0x7FFFu + ((u >> 16) & 1u);
    return (unsigned short)(r >> 16);
}
__device__ inline float bf16_to_f(unsigned short h) {
    return __uint_as_float((unsigned)h << 16);
}
// split x = hi + mid + lo (each bf16), residual <= 2^-27 |x|
__device__ inline void split3(const float* v, short8& h8, short8& m8, short8& l8) {
#pragma unroll
    for (int j = 0; j < 8; ++j) {
        float x = v[j];
        unsigned short h = bf16_rne(x);
        float m_ = x - bf16_to_f(h);
        unsigned short m = bf16_rne(m_);
        float l_ = m_ - bf16_to_f(m);
        unsigned short l = bf16_rne(l_);
        h8[j] = (short)h; m8[j] = (short)m; l8[j] = (short)l;
    }
}

// ---------------------------------------------------------------------------
// Combined prep: blocks 0..7 pre-split W into MFMA-lane-ordered bf16 hi/mid/lo;
// block 8 computes negwn[k] = -0.5*||W_k||^2.
__global__ __launch_bounds__(256) void prep_kernel(
    const float* __restrict__ W, ushort* __restrict__ whi,
    ushort* __restrict__ wmid, ushort* __restrict__ wlo,
    float* __restrict__ negwn) {
    if (blockIdx.x == 8) {
        for (int k = threadIdx.x; k < KCODE; k += 256) {
            const float4* wr = reinterpret_cast<const float4*>(&W[(size_t)k * DDIM]);
            float s = 0.f;
#pragma unroll
            for (int i = 0; i < DDIM / 4; ++i) {
                float4 v = wr[i];
                s += v.x * v.x + v.y * v.y + v.z * v.z + v.w * v.w;
            }
            negwn[k] = -0.5f * s;
        }
        return;
    }
    int t = blockIdx.x * 256 + threadIdx.x;  // 0..2047
    int lane = t & 63;
    int code = (t >> 6) * 16 + (lane & 15);
    int kbase = (lane >> 4) * 8;
    int obase = t * 16;
#pragma unroll
    for (int kh = 0; kh < 2; ++kh) {
        float xbuf[8];
#pragma unroll
        for (int j = 0; j < 8; ++j) xbuf[j] = W[code * 64 + kh * 32 + kbase + j];
        short8 h8, m8, l8;
        split3(xbuf, h8, m8, l8);
#pragma unroll
        for (int j = 0; j < 8; ++j) {
            whi[obase + kh * 8 + j]  = (ushort)h8[j];
            wmid[obase + kh * 8 + j] = (ushort)m8[j];
            wlo[obase + kh * 8 + j]  = (ushort)l8[j];
        }
    }
}

// ---------------------------------------------------------------------------
// Main: 256 threads = 4 waves; wave owns 32 rows (two 16x16 A-tiles).
// Loops 32 chunks of 16 codes; 24 MFMA/chunk; running argmax of dot - ||w||^2/2.
// Epilogue streams quantized_st + the dense one-hot rows (dwordx4, nontemporal).
__global__ __launch_bounds__(256) void vq_main_kernel(
    const float* __restrict__ X, const ushort* __restrict__ WHI,
    const ushort* __restrict__ WMID, const ushort* __restrict__ WLO,
    const float* __restrict__ negwn, const float* __restrict__ W,
    float* __restrict__ counts, float* __restrict__ sse_g,
    int* __restrict__ idx_out, float* __restrict__ outq, float* __restrict__ enc) {

    __shared__ int rowIdx[128];
    const int tid = threadIdx.x;
    const int wave = tid >> 6, lane = tid & 63;
    const int col = lane & 15, kg = lane >> 4;
    const int row0 = blockIdx.x * 128;
    const int rowbase = row0 + wave * 32;

    // Load + 3-way split the two X tiles (A-frag layout: row=lane&15, k=(lane>>4)*8+j)
    short8 xh[2][2], xm[2][2], xl[2][2];
#pragma unroll
    for (int t = 0; t < 2; ++t) {
        int row = rowbase + t * 16 + col;
#pragma unroll
        for (int kh = 0; kh < 2; ++kh) {
            const float4* p = reinterpret_cast<const float4*>(&X[row * 64 + kh * 32 + kg * 8]);
            float4 a = p[0], b = p[1];
            float xbuf[8] = {a.x, a.y, a.z, a.w, b.x, b.y, b.z, b.w};
            split3(xbuf, xh[t][kh], xm[t][kh], xl[t][kh]);
        }
    }

    float bestV[2][4]; int bestC[2][4];
#pragma unroll
    for (int t = 0; t < 2; ++t)
#pragma unroll
        for (int i = 0; i < 4; ++i) { bestV[t][i] = -3.4e38f; bestC[t][i] = 0; }

    for (int c = 0; c < 32; ++c) {
        const short8* ph = reinterpret_cast<const short8*>(&WHI[(c * 64 + lane) * 16]);
        const short8* pm = reinterpret_cast<const short8*>(&WMID[(c * 64 + lane) * 16]);
        const short8* pl = reinterpret_cast<const short8*>(&WLO[(c * 64 + lane) * 16]);
        short8 wh0 = ph[0], wh1 = ph[1];
        short8 wm0 = pm[0], wm1 = pm[1];
        short8 wl0 = pl[0], wl1 = pl[1];
        float wn = negwn[c * 16 + col];
#pragma unroll
        for (int t = 0; t < 2; ++t) {
            f32x4 acc = {0.f, 0.f, 0.f, 0.f};
            // small terms first: x_h*w_l, x_l*w_h, x_m*w_m, x_h*w_m, x_m*w_h, x_h*w_h
            acc = MFMA(xh[t][0], wl0, acc); acc = MFMA(xh[t][1], wl1, acc);
            acc = MFMA(xl[t][0], wh0, acc); acc = MFMA(xl[t][1], wh1, acc);
            acc = MFMA(xm[t][0], wm0, acc); acc = MFMA(xm[t][1], wm1, acc);
            acc = MFMA(xh[t][0], wm0, acc); acc = MFMA(xh[t][1], wm1, acc);
            acc = MFMA(xm[t][0], wh0, acc); acc = MFMA(xm[t][1], wh1, acc);
            acc = MFMA(xh[t][0], wh0, acc); acc = MFMA(xh[t][1], wh1, acc);
#pragma unroll
            for (int i = 0; i < 4; ++i) {
                float r = acc[i] + wn;   // = dot - ||w||^2/2 ; argmax r == argmin dist
                if (r > bestV[t][i]) { bestV[t][i] = r; bestC[t][i] = c; }
            }
        }
    }

    // cross-lane argmax over the 16 cols; ties -> lower code index
#pragma unroll
    for (int t = 0; t < 2; ++t)
#pragma unroll
        for (int i = 0; i < 4; ++i) {
            float v = bestV[t][i];
            int ix = bestC[t][i] * 16 + col;
#pragma unroll
            for (int m = 1; m <= 8; m <<= 1) {
                float ov = __shfl_xor(v, m);
                int   oi = __shfl_xor(ix, m);
                if (ov > v || (ov == v && oi < ix)) { v = ov; ix = oi; }
            }
            if (col == 0) rowIdx[wave * 32 + t * 16 + kg * 4 + i] = ix;
        }
    __syncthreads();

    // epilogue 1: quantized_st, sse
    float ssel = 0.f;
    for (int u = tid; u < 128 * 16; u += 256) {
        int r = u >> 4, d4 = (u & 15) << 2;
        int ix = rowIdx[r];
        float4 wv = *reinterpret_cast<const float4*>(&W[ix * 64 + d4]);
        float4 xv = *reinterpret_cast<const float4*>(&X[(size_t)(row0 + r) * 64 + d4]);
        float dx = wv.x - xv.x, dy = wv.y - xv.y, dz = wv.z - xv.z, dw4 = wv.w - xv.w;
        ssel += dx * dx + dy * dy + dz * dz + dw4 * dw4;
        size_t ob = (size_t)(row0 + r) * 64 + d4;
        outq[ob + 0] = xv.x + dx;
        outq[ob + 1] = xv.y + dy;
        outq[ob + 2] = xv.z + dz;
        outq[ob + 3] = xv.w + dw4;
    }
#pragma unroll
    for (int m = 32; m >= 1; m >>= 1) ssel += __shfl_xor(ssel, m);
    if (lane == 0) atomicAdd(sse_g, ssel);

    if (tid < 128) {
        int ix = rowIdx[tid];
        idx_out[row0 + tid] = ix;
        atomicAdd(&counts[ix], 1.0f);
    }

    // epilogue 2: dense one-hot as one flat 256KB stream per block.
    // Block region: enc[row0*512 .. +65536), byte base ≡ 8 mod 16.
    // Layout: f32x2 head (flats 0,1) + 16383 aligned f32x4 (flats 2..65534)
    //         + f32x2 tail (flats 65534,65535). All nontemporal.
    {
        float* base = enc + ((size_t)row0 << 9);
        if (tid == 0) {
            f32x2 h;
            h.x = (rowIdx[0] == 0) ? 1.0f : 0.0f;
            h.y = (rowIdx[0] == 1) ? 1.0f : 0.0f;
            __builtin_nontemporal_store(h, reinterpret_cast<f32x2*>(base));
        }
        if (tid == 255) {
            f32x2 tl;
            tl.x = (rowIdx[127] == 510) ? 1.0f : 0.0f;
            tl.y = (rowIdx[127] == 511) ? 1.0f : 0.0f;
            __builtin_nontemporal_store(tl, reinterpret_cast<f32x2*>(base + 65534));
        }
#pragma unroll 4
        for (int iter = 0; iter < 64; ++iter) {
            int k = iter * 256 + tid;
            if (k < 16383) {
                int f = 2 + (k << 2);
                f32x4 v;
                v.x = (rowIdx[(f + 0) >> 9] == ((f + 0) & 511)) ? 1.0f : 0.0f;
                v.y = (rowIdx[(f + 1) >> 9] == ((f + 1) & 511)) ? 1.0f : 0.0f;
                v.z = (rowIdx[(f + 2) >> 9] == ((f + 2) & 511)) ? 1.0f : 0.0f;
                v.w = (rowIdx[(f + 3) >> 9] == ((f + 3) & 511)) ? 1.0f : 0.0f;
                __builtin_nontemporal_store(v, reinterpret_cast<f32x4*>(base + f));
            }
        }
    }
}

// ---------------------------------------------------------------------------
// exclusive prefix of counts -> off, pos
__global__ void prefix_kernel(const float* __restrict__ counts,
                              int* __restrict__ off, int* __restrict__ pos) {
    __shared__ int tmp[512];
    int t = threadIdx.x;
    int c = (int)counts[t];
    tmp[t] = c;
    __syncthreads();
    int val = c;
    for (int s = 1; s < 512; s <<= 1) {
        int add = (t >= s) ? tmp[t - s] : 0;
        __syncthreads();
        val += add; tmp[t] = val;
        __syncthreads();
    }
    int excl = val - c;
    off[t] = excl; pos[t] = excl;
}

// bucket[p] = (k << 17) | row   (k < 2^9, row < 2^17)
__global__ void scatter_kernel(const int* __restrict__ idx, int* __restrict__ pos,
                               int* __restrict__ bucket) {
    int i = blockIdx.x * 256 + threadIdx.x;
    int k = idx[i];
    int p = atomicAdd(&pos[k], 1);
    bucket[p] = (k << 17) | i;
}

// Segmented gather-sum over the sorted bucket: one wave per 16 entries,
// lane = dim, flush partial sum via atomicAdd on code-run boundaries.
__global__ __launch_bounds__(256) void dwsum_kernel(
    const float* __restrict__ X, const int* __restrict__ bucket,
    float* __restrict__ dw) {
    const int lane = threadIdx.x & 63;
    const int gwave = (blockIdx.x * 256 + threadIdx.x) >> 6;
    const int r0 = gwave * 16;
    int v = bucket[r0];
    int k = v >> 17, row = v & 0x1FFFF;
    float acc = 0.f;
#pragma unroll
    for (int i = 0; i < 16; ++i) {
        acc += X[(size_t)row * 64 + lane];
        if (i + 1 < 16) {
            int nv = bucket[r0 + i + 1];
            int nk = nv >> 17, nrow = nv & 0x1FFFF;
            if (nk != k) {                // wave-uniform branch
                atomicAdd(&dw[k * 64 + lane], acc);
                acc = 0.f; k = nk;
            }
            row = nrow;
        }
    }
    atomicAdd(&dw[k * 64 + lane], acc);
}

// ---------------------------------------------------------------------------
__global__ __launch_bounds__(512) void finalize_kernel(
    const float* __restrict__ ema_w, const float* __restrict__ ema_cs,
    const float* __restrict__ counts, const float* __restrict__ dw,
    const float* __restrict__ sse_g, float* __restrict__ out) {

    __shared__ float red[512];
    __shared__ float cs_sh[512];
    int t = threadIdx.x;

    float cnt = counts[t];
    float raw = ema_cs[t] * 0.99f + 0.01f * cnt;
    red[t] = raw;
    __syncthreads();
    for (int s = 256; s > 0; s >>= 1) {
        if (t < s) red[t] += red[t + s];
        __syncthreads();
    }
    float n = red[0];
    __syncthreads();

    float ncs = (raw + 1e-5f) / (n + (float)KCODE * 1e-5f) * n;
    out[CS_OFF + t] = ncs;
    cs_sh[t] = ncs;

    float avg = cnt / (float)NROWS;
    red[t] = avg * logf(avg + 1e-10f);
    __syncthreads();
    for (int s = 256; s > 0; s >>= 1) {
        if (t < s) red[t] += red[t + s];
        __syncthreads();
    }
    if (t == 0) {
        out[PERP_OFF] = expf(-red[0]);
        out[0] = 0.25f * sse_g[0] / ((float)NROWS * (float)DDIM);
    }
    __syncthreads();

    for (int i = t; i < KCODE * DDIM; i += 512) {
        float ne = ema_w[i] * 0.99f + 0.01f * dw[i];
        out[EMAW_OFF + i] = ne;
        out[EMB_OFF + i] = ne / cs_sh[i >> 6];
    }
}

// ---------------------------------------------------------------------------
extern "C" void kernel_launch(void* const* d_in, const int* in_sizes, int n_in,
                              void* d_out, int out_size, void* d_ws, size_t ws_size,
                              hipStream_t stream) {
    const float* X      = (const float*)d_in[0];
    const float* W      = (const float*)d_in[1];
    const float* ema_w  = (const float*)d_in[2];
    const float* ema_cs = (const float*)d_in[3];
    float* out = (float*)d_out;
    float* ws  = (float*)d_ws;

    float*  counts = ws + WS_COUNTS;
    float*  negwn  = ws + WS_NEGWN;
    float*  sse    = ws + WS_SSE;
    float*  dw     = ws + WS_DW;
    int*    off    = (int*)(ws + WS_OFF);
    int*    pos    = (int*)(ws + WS_POS);
    int*    idx    = (int*)(ws + WS_IDX);
    int*    bucket = (int*)(ws + WS_BUCKET);
    ushort* whi    = (ushort*)(ws + WS_WHI);
    ushort* wmid   = (ushort*)(ws + WS_WMID);
    ushort* wlo    = (ushort*)(ws + WS_WLO);

    // zero counts + negwn + sse + dw (small; one-hot region is fully written
    // by vq_main's epilogue)
    (void)hipMemsetAsync(d_ws, 0, (size_t)WS_ZERO_FLOATS * sizeof(float), stream);

    prep_kernel<<<9, 256, 0, stream>>>(W, whi, wmid, wlo, negwn);
    vq_main_kernel<<<NROWS / 128, 256, 0, stream>>>(X, whi, wmid, wlo, negwn, W,
                                                    counts, sse, idx,
                                                    out + QUANT_OFF, out + ENC_OFF);
    prefix_kernel<<<1, 512, 0, stream>>>(counts, off, pos);
    scatter_kernel<<<NROWS / 256, 256, 0, stream>>>(idx, pos, bucket);
    dwsum_kernel<<<NROWS / 16 / 4, 256, 0, stream>>>(X, bucket, dw);
    finalize_kernel<<<1, 512, 0, stream>>>(ema_w, ema_cs, counts, dw, sse, out);
}